// Round 2
// baseline (683.394 us; speedup 1.0000x reference)
//
#include <hip/hip_runtime.h>
#include <hip/hip_bf16.h>
#include <hip/hip_fp16.h>

// Round 2: dtype-robust fused kernel + LDS reduced to 40960 B.
// Kernel 1 classifies the input dtype (bf16 / fp32 / fp16) from Wq's bit
// patterns into a flag in d_ws; kernel 2 (one block per (b,n)) does
// QKV-FC -> causal attention over T -> two output FCs, branching
// block-uniformly on the flag for all global loads/stores.

typedef unsigned short u16;
typedef unsigned int u32;
typedef unsigned long long u64;

#define B_ 32
#define T_ 24
#define N_ 325
#define D_ 64
#define K2_ 128   // 2*D
#define NO_ 192   // 3*D

__device__ __forceinline__ float bf2f(u16 u) { return __uint_as_float(((u32)u) << 16); }
__device__ __forceinline__ u16 f2bf(float f) {
    u32 u = __float_as_uint(f);
    u32 r = (u + 0x7FFFu + ((u >> 16) & 1u)) >> 16;  // RNE
    return (u16)r;
}
__device__ __forceinline__ u32 pack2(float a, float b) {
    return (u32)f2bf(a) | ((u32)f2bf(b) << 16);
}
__device__ __forceinline__ u16 f2h(float f) {
    __half h = __float2half(f);
    return *reinterpret_cast<u16*>(&h);
}
__device__ __forceinline__ u32 packh2(float a, float b) {
    return (u32)f2h(a) | ((u32)f2h(b) << 16);
}
__device__ __forceinline__ float h2f(u16 bits) {
    __half h;
    *reinterpret_cast<u16*>(&h) = bits;
    return __half2float(h);
}

// dt: 0 = fp32, 1 = bf16, 2 = fp16 (dt is block-uniform everywhere)
__device__ __forceinline__ float loadf(const void* p, int i, int dt) {
    if (dt == 0) return ((const float*)p)[i];
    u16 v = ((const u16*)p)[i];
    return (dt == 1) ? bf2f(v) : h2f(v);
}

// load 8 consecutive elements at element-index idx (idx % 8 == 0) -> 8 bf16 in LDS
__device__ __forceinline__ void load8_bf16(const void* p, int idx, int dt, u16* dst) {
    if (dt == 1) {
        *(uint4*)dst = *(const uint4*)((const u16*)p + idx);
    } else if (dt == 0) {
        const float* f = (const float*)p + idx;
        float4 a = *(const float4*)f;
        float4 b = *(const float4*)(f + 4);
        uint4 o;
        o.x = pack2(a.x, a.y); o.y = pack2(a.z, a.w);
        o.z = pack2(b.x, b.y); o.w = pack2(b.z, b.w);
        *(uint4*)dst = o;
    } else {
        uint4 v = *(const uint4*)((const u16*)p + idx);
        uint4 o;
        o.x = pack2(h2f((u16)v.x), h2f((u16)(v.x >> 16)));
        o.y = pack2(h2f((u16)v.y), h2f((u16)(v.y >> 16)));
        o.z = pack2(h2f((u16)v.z), h2f((u16)(v.z >> 16)));
        o.w = pack2(h2f((u16)v.w), h2f((u16)(v.w >> 16)));
        *(uint4*)dst = o;
    }
}

__device__ __forceinline__ void store4(void* p, int idx, int dt,
                                       float a, float b, float c, float d) {
    if (dt == 1) {
        uint2 st; st.x = pack2(a, b); st.y = pack2(c, d);
        *(uint2*)((u16*)p + idx) = st;
    } else if (dt == 0) {
        float4 v; v.x = a; v.y = b; v.z = c; v.w = d;
        *(float4*)((float*)p + idx) = v;
    } else {
        uint2 st; st.x = packh2(a, b); st.y = packh2(c, d);
        *(uint2*)((u16*)p + idx) = st;
    }
}

// Classify dtype from Wq (values ~0.02*N(0,1)). For each 32-bit word, look at
// bits [14:7] of the LOW 16 bits: bf16 data -> sane bf16 exponent [108,126];
// fp16 data -> 8*exp+mant3 in [8,103]; fp32 data -> random mantissa bits.
__global__ void ta_classify(const u32* __restrict__ wq, int* __restrict__ flag) {
    u32 w = wq[threadIdx.x];
    u32 ef = (w >> 7) & 0xFFu;
    u64 mb = __ballot(ef >= 108 && ef <= 126);
    u64 mh = __ballot(ef >= 8 && ef <= 103);
    if (threadIdx.x == 0) {
        int dt = (__popcll(mb) >= 40) ? 1 : ((__popcll(mh) >= 44) ? 2 : 0);
        *flag = dt;
    }
}

__global__ __launch_bounds__(256) void ta_fused(
    const void* __restrict__ x,   const void* __restrict__ ste,
    const void* __restrict__ Wq,  const void* __restrict__ bq,
    const void* __restrict__ Wk,  const void* __restrict__ bk,
    const void* __restrict__ Wv,  const void* __restrict__ bv,
    const void* __restrict__ Wo1, const void* __restrict__ bo1,
    const void* __restrict__ Wo2, const void* __restrict__ bo2,
    void* __restrict__ out, const int* __restrict__ flagp)
{
    // LDS (40960 B):
    //  [0,6144)      sh_h : bf16 [24][128]   -> later o_s fp32 [24][64]
    //  [6144,24576)  qkv_f: fp32 [24][192]   -> later tmp fp32 [24][64] (first 6144 B)
    //  [24576,40960) wbuf : bf16 [128][64]   (Wq->Wk->Wv, then [Wo1|Wo2] as [2][64][64])
    __shared__ __align__(16) char smem[40960];
    u16*   sh_h  = (u16*)smem;
    float* qkv_f = (float*)(smem + 6144);
    u16*   wbuf  = (u16*)(smem + 24576);

    const int tid = threadIdx.x;
    const int n = blockIdx.x;
    const int b = blockIdx.y;
    const int dt = flagp ? *flagp : 1;

    // ---------------- Phase A: stage h = [x|ste] (bf16) and Wq ----------------
    for (int i = tid; i < 384; i += 256) {
        int f = i * 8;
        int t = f >> 7, kk = f & 127;
        int base = ((b * T_ + t) * N_ + n) * D_;
        if (kk < D_) load8_bf16(x,   base + kk,      dt, sh_h + f);
        else         load8_bf16(ste, base + kk - 64, dt, sh_h + f);
    }
    for (int i = tid; i < 1024; i += 256) load8_bf16(Wq, i * 8, dt, wbuf + i * 8);
    __syncthreads();

    // ---------------- Phase B: q, k, v = relu(h @ W + bias), one W at a time ----------------
    const void* Wm[3] = {Wq, Wk, Wv};
    const void* bm[3] = {bq, bk, bv};
    #pragma unroll
    for (int m = 0; m < 3; ++m) {
        {
            const int jq = tid & 15, tg = tid >> 4;   // rows tg and (tg<8 ? tg+16 : -)
            const int j0 = jq * 4;
            float a0[4], a1[4];
            #pragma unroll
            for (int c = 0; c < 4; ++c) { float bb = loadf(bm[m], j0 + c, dt); a0[c] = bb; a1[c] = bb; }
            for (int kk = 0; kk < K2_; kk += 2) {
                uint2 wa = *(const uint2*)(wbuf + kk * 64 + j0);
                uint2 wb = *(const uint2*)(wbuf + (kk + 1) * 64 + j0);
                float wa0 = bf2f((u16)wa.x), wa1 = bf2f((u16)(wa.x >> 16));
                float wa2 = bf2f((u16)wa.y), wa3 = bf2f((u16)(wa.y >> 16));
                float wb0 = bf2f((u16)wb.x), wb1 = bf2f((u16)(wb.x >> 16));
                float wb2 = bf2f((u16)wb.y), wb3 = bf2f((u16)(wb.y >> 16));
                u32 hp0 = *(const u32*)(sh_h + tg * K2_ + kk);
                float h00 = bf2f((u16)hp0), h01 = bf2f((u16)(hp0 >> 16));
                a0[0] = fmaf(h00, wa0, a0[0]); a0[0] = fmaf(h01, wb0, a0[0]);
                a0[1] = fmaf(h00, wa1, a0[1]); a0[1] = fmaf(h01, wb1, a0[1]);
                a0[2] = fmaf(h00, wa2, a0[2]); a0[2] = fmaf(h01, wb2, a0[2]);
                a0[3] = fmaf(h00, wa3, a0[3]); a0[3] = fmaf(h01, wb3, a0[3]);
                if (tg < 8) {                          // wave-uniform
                    u32 hp1 = *(const u32*)(sh_h + (tg + 16) * K2_ + kk);
                    float h10 = bf2f((u16)hp1), h11 = bf2f((u16)(hp1 >> 16));
                    a1[0] = fmaf(h10, wa0, a1[0]); a1[0] = fmaf(h11, wb0, a1[0]);
                    a1[1] = fmaf(h10, wa1, a1[1]); a1[1] = fmaf(h11, wb1, a1[1]);
                    a1[2] = fmaf(h10, wa2, a1[2]); a1[2] = fmaf(h11, wb2, a1[2]);
                    a1[3] = fmaf(h10, wa3, a1[3]); a1[3] = fmaf(h11, wb3, a1[3]);
                }
            }
            float4 v0; v0.x = fmaxf(a0[0], 0.f); v0.y = fmaxf(a0[1], 0.f);
                       v0.z = fmaxf(a0[2], 0.f); v0.w = fmaxf(a0[3], 0.f);
            *(float4*)(qkv_f + tg * NO_ + m * 64 + j0) = v0;
            if (tg < 8) {
                float4 v1; v1.x = fmaxf(a1[0], 0.f); v1.y = fmaxf(a1[1], 0.f);
                           v1.z = fmaxf(a1[2], 0.f); v1.w = fmaxf(a1[3], 0.f);
                *(float4*)(qkv_f + (tg + 16) * NO_ + m * 64 + j0) = v1;
            }
        }
        __syncthreads();
        if (m < 2) {
            for (int i = tid; i < 1024; i += 256) load8_bf16(Wm[m + 1], i * 8, dt, wbuf + i * 8);
            __syncthreads();
        }
    }

    // ---------------- Phase C: stage [Wo1|Wo2] into wbuf + attention ----------------
    for (int i = tid; i < 1024; i += 256) {
        if (i < 512) load8_bf16(Wo1, i * 8, dt, wbuf + i * 8);
        else         load8_bf16(Wo2, (i - 512) * 8, dt, wbuf + i * 8);
    }
    float* o_s = (float*)smem;                        // [24][64] fp32 (sh_h dead)
    if (tid < 192) {
        const int hi = tid / 24, t = tid - hi * 24;
        float qr[8];
        #pragma unroll
        for (int d = 0; d < 8; ++d) qr[d] = qkv_f[t * NO_ + hi * 8 + d];
        float e[24];
        float mx = -3.0e38f;
        #pragma unroll
        for (int s = 0; s < T_; ++s) {
            float dot = 0.f;
            #pragma unroll
            for (int d = 0; d < 8; ++d)
                dot = fmaf(qr[d], qkv_f[s * NO_ + 64 + hi * 8 + d], dot);
            float l = (s <= t) ? dot * 0.35355339059327373f : -32767.0f;
            e[s] = l;
            mx = fmaxf(mx, l);
        }
        float sum = 0.f;
        #pragma unroll
        for (int s = 0; s < T_; ++s) { float ee = __expf(e[s] - mx); e[s] = ee; sum += ee; }
        float inv = 1.0f / sum;
        float ov[8];
        #pragma unroll
        for (int d = 0; d < 8; ++d) ov[d] = 0.f;
        #pragma unroll
        for (int s = 0; s < T_; ++s) {
            float p = e[s] * inv;
            #pragma unroll
            for (int d = 0; d < 8; ++d)
                ov[d] = fmaf(p, qkv_f[s * NO_ + 128 + hi * 8 + d], ov[d]);
        }
        #pragma unroll
        for (int d = 0; d < 8; ++d) o_s[t * D_ + hi * 8 + d] = ov[d];
    }
    __syncthreads();

    // ---------------- Phase D1: tmp = relu(o @ Wo1 + bo1) ----------------
    float* tmp = qkv_f;                               // [24][64] fp32 (qkv dead)
    {
        const int jq = tid & 15, tg = tid >> 4;
        const int j0 = jq * 4;
        float a0[4], a1[4];
        #pragma unroll
        for (int c = 0; c < 4; ++c) { float bb = loadf(bo1, j0 + c, dt); a0[c] = bb; a1[c] = bb; }
        for (int kk = 0; kk < D_; ++kk) {
            uint2 wv = *(const uint2*)(wbuf + kk * 64 + j0);
            float w0 = bf2f((u16)wv.x), w1 = bf2f((u16)(wv.x >> 16));
            float w2 = bf2f((u16)wv.y), w3 = bf2f((u16)(wv.y >> 16));
            float hA = o_s[tg * D_ + kk];
            a0[0] = fmaf(hA, w0, a0[0]); a0[1] = fmaf(hA, w1, a0[1]);
            a0[2] = fmaf(hA, w2, a0[2]); a0[3] = fmaf(hA, w3, a0[3]);
            if (tg < 8) {
                float hB = o_s[(tg + 16) * D_ + kk];
                a1[0] = fmaf(hB, w0, a1[0]); a1[1] = fmaf(hB, w1, a1[1]);
                a1[2] = fmaf(hB, w2, a1[2]); a1[3] = fmaf(hB, w3, a1[3]);
            }
        }
        float4 v0; v0.x = fmaxf(a0[0], 0.f); v0.y = fmaxf(a0[1], 0.f);
                   v0.z = fmaxf(a0[2], 0.f); v0.w = fmaxf(a0[3], 0.f);
        *(float4*)(tmp + tg * D_ + j0) = v0;
        if (tg < 8) {
            float4 v1; v1.x = fmaxf(a1[0], 0.f); v1.y = fmaxf(a1[1], 0.f);
                       v1.z = fmaxf(a1[2], 0.f); v1.w = fmaxf(a1[3], 0.f);
            *(float4*)(tmp + (tg + 16) * D_ + j0) = v1;
        }
    }
    __syncthreads();

    // ---------------- Phase D2: out = tmp @ Wo2 + bo2 ----------------
    {
        const int jq = tid & 15, tg = tid >> 4;
        const int j0 = jq * 4;
        const u16* w2p = wbuf + 4096;
        float a0[4], a1[4];
        #pragma unroll
        for (int c = 0; c < 4; ++c) { float bb = loadf(bo2, j0 + c, dt); a0[c] = bb; a1[c] = bb; }
        for (int kk = 0; kk < D_; ++kk) {
            uint2 wv = *(const uint2*)(w2p + kk * 64 + j0);
            float w0 = bf2f((u16)wv.x), w1 = bf2f((u16)(wv.x >> 16));
            float w2 = bf2f((u16)wv.y), w3 = bf2f((u16)(wv.y >> 16));
            float hA = tmp[tg * D_ + kk];
            a0[0] = fmaf(hA, w0, a0[0]); a0[1] = fmaf(hA, w1, a0[1]);
            a0[2] = fmaf(hA, w2, a0[2]); a0[3] = fmaf(hA, w3, a0[3]);
            if (tg < 8) {
                float hB = tmp[(tg + 16) * D_ + kk];
                a1[0] = fmaf(hB, w0, a1[0]); a1[1] = fmaf(hB, w1, a1[1]);
                a1[2] = fmaf(hB, w2, a1[2]); a1[3] = fmaf(hB, w3, a1[3]);
            }
        }
        int base0 = ((b * T_ + tg) * N_ + n) * D_ + j0;
        store4(out, base0, dt, a0[0], a0[1], a0[2], a0[3]);
        if (tg < 8) {
            int base1 = ((b * T_ + tg + 16) * N_ + n) * D_ + j0;
            store4(out, base1, dt, a1[0], a1[1], a1[2], a1[3]);
        }
    }
}

extern "C" void kernel_launch(void* const* d_in, const int* in_sizes, int n_in,
                              void* d_out, int out_size, void* d_ws, size_t ws_size,
                              hipStream_t stream) {
    (void)in_sizes; (void)n_in; (void)out_size;
    int* flag = (ws_size >= sizeof(int)) ? (int*)d_ws : nullptr;
    if (flag) {
        ta_classify<<<dim3(1), dim3(64), 0, stream>>>((const u32*)d_in[2], flag);
    }
    dim3 grid(N_, B_);
    ta_fused<<<grid, dim3(256), 0, stream>>>(
        d_in[0], d_in[1], d_in[2], d_in[3], d_in[4], d_in[5],
        d_in[6], d_in[7], d_in[8], d_in[9], d_in[10], d_in[11],
        d_out, flag);
}

// Round 7
// 249.035 us; speedup vs baseline: 2.7442x; 2.7442x over previous
//
#include <hip/hip_runtime.h>
#include <hip/hip_bf16.h>

// Round 7: r6's MFMA pipeline with the CORRECT dtype: fp32 inputs/outputs
// (r2's WRITE_SIZE=62400KB == out_size*4B proved the output is fp32; r2 passed
// via its runtime fp32 path; r3-r6 NaN'd by reading fp32 bits as bf16).
// Internally: h/W converted to bf16 (r2-validated precision), fp32 accum,
// fp32 VALU attention, fp32 output stores.

typedef unsigned short u16;
typedef unsigned int u32;
typedef __attribute__((ext_vector_type(8))) short bf16x8;
typedef __attribute__((ext_vector_type(4))) float f32x4;

#define B_ 32
#define T_ 24
#define N_ 325
#define D_ 64

#define WQKV_OFF 0        // 3072 frags * 8 el = 24576 el
#define WO1_OFF  24576    // 512 frags  * 8 el = 4096 el
#define WO2_OFF  28672    // 512 frags  * 8 el = 4096 el
#define WS_ELS   32768

__device__ __align__(64) u16 g_ws[WS_ELS];

__device__ __forceinline__ u16 f2bf(float f) {
    u32 u = __float_as_uint(f);
    return (u16)((u + 0x7FFFu + ((u >> 16) & 1u)) >> 16);  // RNE
}
__device__ __forceinline__ u32 pack2(float a, float b) {
    return (u32)f2bf(a) | ((u32)f2bf(b) << 16);
}

// B-frag (16x16x32): lane l holds B[k = ks*32 + (l>>4)*8 + j][n = nt*16 + (l&15)]
// fp32 weight sources -> bf16 scalar stores into aligned g_ws.
__global__ void ta_repack(const float* __restrict__ Wq, const float* __restrict__ Wk,
                          const float* __restrict__ Wv, const float* __restrict__ Wo1,
                          const float* __restrict__ Wo2) {
    int f = blockIdx.x * 256 + threadIdx.x;   // 0..4095
    const float* src;
    u16* dst;
    if (f < 3072) {
        int nt = f >> 8, ks = (f >> 6) & 3, l = f & 63;
        int nn = nt * 16 + (l & 15);
        int kb = ks * 32 + ((l >> 4) & 3) * 8;
        const float* W = (nn < 64) ? Wq : (nn < 128 ? Wk : Wv);
        src = W + kb * 64 + (nn & 63);
        dst = g_ws + WQKV_OFF + f * 8;
    } else {
        int fo = f - 3072;
        int m = fo >> 9;
        int fi = fo & 511;
        int nt = fi >> 7, ks = (fi >> 6) & 1, l = fi & 63;
        int nn = nt * 16 + (l & 15);
        int kb = ks * 32 + ((l >> 4) & 3) * 8;
        src = (m ? Wo2 : Wo1) + kb * 64 + nn;
        dst = g_ws + (m ? WO2_OFF : WO1_OFF) + fi * 8;
    }
    #pragma unroll
    for (int j = 0; j < 8; ++j) dst[j] = f2bf(src[j * 64]);
}

// LDS layout — fully disjoint, all zero-initialized:
//  [0,      8704)  sh_h   u16 [32][136]
//  [8704,  13312)  sh_o   u16 [32][72]
//  [13312, 17920)  sh_tmp u16 [32][72]
//  [17920, 26624)  sh_q   f32 [32][68]
//  [26624, 35328)  sh_k   f32 [32][68]
//  [35328, 44032)  sh_v   f32 [32][68]
#define SMEM_BYTES 44032

__global__ __launch_bounds__(256) void ta_mfma(
    const float* __restrict__ x,   const float* __restrict__ ste,
    const float* __restrict__ bq,  const float* __restrict__ bk,
    const float* __restrict__ bv,  const float* __restrict__ bo1,
    const float* __restrict__ bo2, float* __restrict__ out)
{
    __shared__ __align__(16) char smem[SMEM_BYTES];
    u16*   sh_h   = (u16*)smem;
    u16*   sh_o   = (u16*)(smem + 8704);
    u16*   sh_tmp = (u16*)(smem + 13312);
    float* sh_q   = (float*)(smem + 17920);
    float* sh_k   = (float*)(smem + 26624);
    float* sh_v   = (float*)(smem + 35328);

    const int tid  = threadIdx.x;
    const int w    = tid >> 6;
    const int l    = tid & 63;
    const int l15  = l & 15;
    const int quad = l >> 4;
    const int n = blockIdx.x;
    const int b = blockIdx.y;

    // ---------------- Phase 0: zero ALL LDS ----------------
    {
        uint4 z; z.x = z.y = z.z = z.w = 0u;
        for (int i = tid; i < SMEM_BYTES / 16; i += 256)
            *(uint4*)(smem + i * 16) = z;
    }
    __syncthreads();

    // ---------------- Phase A: stage h rows 0..23 (fp32 -> bf16) ----------------
    for (int i = tid; i < 384; i += 256) {
        int f = i * 8;
        int t = f >> 7, kk = f & 127;
        int gbase = ((b * T_ + t) * N_ + n) * D_;
        const float* src = (kk < 64) ? (x + gbase + kk) : (ste + gbase + kk - 64);
        float4 a = *(const float4*)src;
        float4 c = *(const float4*)(src + 4);
        uint4 o;
        o.x = pack2(a.x, a.y); o.y = pack2(a.z, a.w);
        o.z = pack2(c.x, c.y); o.w = pack2(c.z, c.w);
        *(uint4*)(sh_h + t * 136 + kk) = o;
    }
    const int col16 = w * 16 + l15;
    float bqv = bq[col16],  bkv = bk[col16],  bvv = bv[col16];
    float b1v = bo1[col16], b2v = bo2[col16];
    __syncthreads();

    // ---------------- Phase B: qkv = relu(h @ Wqkv + b) via MFMA ----------------
    bf16x8 af0_0 = *(const bf16x8*)(sh_h + l15 * 136 + 0  + quad * 8);
    bf16x8 af0_1 = *(const bf16x8*)(sh_h + l15 * 136 + 32 + quad * 8);
    bf16x8 af0_2 = *(const bf16x8*)(sh_h + l15 * 136 + 64 + quad * 8);
    bf16x8 af0_3 = *(const bf16x8*)(sh_h + l15 * 136 + 96 + quad * 8);
    bf16x8 af1_0 = *(const bf16x8*)(sh_h + (16 + l15) * 136 + 0  + quad * 8);
    bf16x8 af1_1 = *(const bf16x8*)(sh_h + (16 + l15) * 136 + 32 + quad * 8);
    bf16x8 af1_2 = *(const bf16x8*)(sh_h + (16 + l15) * 136 + 64 + quad * 8);
    bf16x8 af1_3 = *(const bf16x8*)(sh_h + (16 + l15) * 136 + 96 + quad * 8);

    // --- Q (nt = w) ---
    {
        const int nt = w;
        f32x4 c0 = {0.f,0.f,0.f,0.f}, c1 = {0.f,0.f,0.f,0.f};
        bf16x8 bf;
        bf = *(const bf16x8*)(g_ws + WQKV_OFF + ((nt*4 + 0)*64 + l)*8);
        c0 = __builtin_amdgcn_mfma_f32_16x16x32_bf16(af0_0, bf, c0, 0,0,0);
        c1 = __builtin_amdgcn_mfma_f32_16x16x32_bf16(af1_0, bf, c1, 0,0,0);
        bf = *(const bf16x8*)(g_ws + WQKV_OFF + ((nt*4 + 1)*64 + l)*8);
        c0 = __builtin_amdgcn_mfma_f32_16x16x32_bf16(af0_1, bf, c0, 0,0,0);
        c1 = __builtin_amdgcn_mfma_f32_16x16x32_bf16(af1_1, bf, c1, 0,0,0);
        bf = *(const bf16x8*)(g_ws + WQKV_OFF + ((nt*4 + 2)*64 + l)*8);
        c0 = __builtin_amdgcn_mfma_f32_16x16x32_bf16(af0_2, bf, c0, 0,0,0);
        c1 = __builtin_amdgcn_mfma_f32_16x16x32_bf16(af1_2, bf, c1, 0,0,0);
        bf = *(const bf16x8*)(g_ws + WQKV_OFF + ((nt*4 + 3)*64 + l)*8);
        c0 = __builtin_amdgcn_mfma_f32_16x16x32_bf16(af0_3, bf, c0, 0,0,0);
        c1 = __builtin_amdgcn_mfma_f32_16x16x32_bf16(af1_3, bf, c1, 0,0,0);
        #pragma unroll
        for (int r = 0; r < 4; ++r) {
            int row0 = quad * 4 + r;
            sh_q[row0 * 68 + col16]        = fmaxf(c0[r] + bqv, 0.f);
            sh_q[(16 + row0) * 68 + col16] = fmaxf(c1[r] + bqv, 0.f);
        }
    }
    // --- K (nt = w + 4) ---
    {
        const int nt = w + 4;
        f32x4 c0 = {0.f,0.f,0.f,0.f}, c1 = {0.f,0.f,0.f,0.f};
        bf16x8 bf;
        bf = *(const bf16x8*)(g_ws + WQKV_OFF + ((nt*4 + 0)*64 + l)*8);
        c0 = __builtin_amdgcn_mfma_f32_16x16x32_bf16(af0_0, bf, c0, 0,0,0);
        c1 = __builtin_amdgcn_mfma_f32_16x16x32_bf16(af1_0, bf, c1, 0,0,0);
        bf = *(const bf16x8*)(g_ws + WQKV_OFF + ((nt*4 + 1)*64 + l)*8);
        c0 = __builtin_amdgcn_mfma_f32_16x16x32_bf16(af0_1, bf, c0, 0,0,0);
        c1 = __builtin_amdgcn_mfma_f32_16x16x32_bf16(af1_1, bf, c1, 0,0,0);
        bf = *(const bf16x8*)(g_ws + WQKV_OFF + ((nt*4 + 2)*64 + l)*8);
        c0 = __builtin_amdgcn_mfma_f32_16x16x32_bf16(af0_2, bf, c0, 0,0,0);
        c1 = __builtin_amdgcn_mfma_f32_16x16x32_bf16(af1_2, bf, c1, 0,0,0);
        bf = *(const bf16x8*)(g_ws + WQKV_OFF + ((nt*4 + 3)*64 + l)*8);
        c0 = __builtin_amdgcn_mfma_f32_16x16x32_bf16(af0_3, bf, c0, 0,0,0);
        c1 = __builtin_amdgcn_mfma_f32_16x16x32_bf16(af1_3, bf, c1, 0,0,0);
        #pragma unroll
        for (int r = 0; r < 4; ++r) {
            int row0 = quad * 4 + r;
            sh_k[row0 * 68 + col16]        = fmaxf(c0[r] + bkv, 0.f);
            sh_k[(16 + row0) * 68 + col16] = fmaxf(c1[r] + bkv, 0.f);
        }
    }
    // --- V (nt = w + 8) ---
    {
        const int nt = w + 8;
        f32x4 c0 = {0.f,0.f,0.f,0.f}, c1 = {0.f,0.f,0.f,0.f};
        bf16x8 bf;
        bf = *(const bf16x8*)(g_ws + WQKV_OFF + ((nt*4 + 0)*64 + l)*8);
        c0 = __builtin_amdgcn_mfma_f32_16x16x32_bf16(af0_0, bf, c0, 0,0,0);
        c1 = __builtin_amdgcn_mfma_f32_16x16x32_bf16(af1_0, bf, c1, 0,0,0);
        bf = *(const bf16x8*)(g_ws + WQKV_OFF + ((nt*4 + 1)*64 + l)*8);
        c0 = __builtin_amdgcn_mfma_f32_16x16x32_bf16(af0_1, bf, c0, 0,0,0);
        c1 = __builtin_amdgcn_mfma_f32_16x16x32_bf16(af1_1, bf, c1, 0,0,0);
        bf = *(const bf16x8*)(g_ws + WQKV_OFF + ((nt*4 + 2)*64 + l)*8);
        c0 = __builtin_amdgcn_mfma_f32_16x16x32_bf16(af0_2, bf, c0, 0,0,0);
        c1 = __builtin_amdgcn_mfma_f32_16x16x32_bf16(af1_2, bf, c1, 0,0,0);
        bf = *(const bf16x8*)(g_ws + WQKV_OFF + ((nt*4 + 3)*64 + l)*8);
        c0 = __builtin_amdgcn_mfma_f32_16x16x32_bf16(af0_3, bf, c0, 0,0,0);
        c1 = __builtin_amdgcn_mfma_f32_16x16x32_bf16(af1_3, bf, c1, 0,0,0);
        #pragma unroll
        for (int r = 0; r < 4; ++r) {
            int row0 = quad * 4 + r;
            sh_v[row0 * 68 + col16]        = fmaxf(c0[r] + bvv, 0.f);
            sh_v[(16 + row0) * 68 + col16] = fmaxf(c1[r] + bvv, 0.f);
        }
    }
    __syncthreads();

    // ---------------- Phase C: attention (VALU) + FC B-frag prefetch ----------------
    bf16x8 w1f0 = *(const bf16x8*)(g_ws + WO1_OFF + ((w*2 + 0)*64 + l)*8);
    bf16x8 w1f1 = *(const bf16x8*)(g_ws + WO1_OFF + ((w*2 + 1)*64 + l)*8);
    bf16x8 w2f0 = *(const bf16x8*)(g_ws + WO2_OFF + ((w*2 + 0)*64 + l)*8);
    bf16x8 w2f1 = *(const bf16x8*)(g_ws + WO2_OFF + ((w*2 + 1)*64 + l)*8);
    {
        const int hi = tid >> 5;
        const int t  = tid & 31;
        if (t < 24) {
            const float* qp = sh_q + t * 68 + hi * 8;
            float qr[8];
            #pragma unroll
            for (int d = 0; d < 8; ++d) qr[d] = qp[d];
            float e[24], mx = -3.0e38f;
            #pragma unroll
            for (int s = 0; s < T_; ++s) {
                const float* kp = sh_k + s * 68 + hi * 8;
                float4 ka = *(const float4*)kp;
                float4 kb2 = *(const float4*)(kp + 4);
                float dot = qr[0] * ka.x;
                dot = fmaf(qr[1], ka.y, dot);  dot = fmaf(qr[2], ka.z, dot);
                dot = fmaf(qr[3], ka.w, dot);  dot = fmaf(qr[4], kb2.x, dot);
                dot = fmaf(qr[5], kb2.y, dot); dot = fmaf(qr[6], kb2.z, dot);
                dot = fmaf(qr[7], kb2.w, dot);
                float lg = (s <= t) ? dot * 0.35355339059327373f : -32767.0f;
                e[s] = lg;
                mx = fmaxf(mx, lg);
            }
            float sum = 0.f;
            #pragma unroll
            for (int s = 0; s < T_; ++s) { float ee = __expf(e[s] - mx); e[s] = ee; sum += ee; }
            float inv = 1.0f / sum;
            float ov[8];
            #pragma unroll
            for (int d = 0; d < 8; ++d) ov[d] = 0.f;
            #pragma unroll
            for (int s = 0; s < T_; ++s) {
                float p = e[s] * inv;
                const float* vp = sh_v + s * 68 + hi * 8;
                float4 va = *(const float4*)vp;
                float4 vb = *(const float4*)(vp + 4);
                ov[0] = fmaf(p, va.x, ov[0]); ov[1] = fmaf(p, va.y, ov[1]);
                ov[2] = fmaf(p, va.z, ov[2]); ov[3] = fmaf(p, va.w, ov[3]);
                ov[4] = fmaf(p, vb.x, ov[4]); ov[5] = fmaf(p, vb.y, ov[5]);
                ov[6] = fmaf(p, vb.z, ov[6]); ov[7] = fmaf(p, vb.w, ov[7]);
            }
            u16* op = sh_o + t * 72 + hi * 8;
            *(u32*)(op + 0) = pack2(ov[0], ov[1]);
            *(u32*)(op + 2) = pack2(ov[2], ov[3]);
            *(u32*)(op + 4) = pack2(ov[4], ov[5]);
            *(u32*)(op + 6) = pack2(ov[6], ov[7]);
        }
    }
    __syncthreads();

    // ---------------- Phase D1: tmp = relu(o @ Wo1 + bo1) ----------------
    {
        bf16x8 a00 = *(const bf16x8*)(sh_o + l15 * 72 + 0  + quad * 8);
        bf16x8 a01 = *(const bf16x8*)(sh_o + l15 * 72 + 32 + quad * 8);
        bf16x8 a10 = *(const bf16x8*)(sh_o + (16 + l15) * 72 + 0  + quad * 8);
        bf16x8 a11 = *(const bf16x8*)(sh_o + (16 + l15) * 72 + 32 + quad * 8);
        f32x4 c0 = {0.f,0.f,0.f,0.f}, c1 = {0.f,0.f,0.f,0.f};
        c0 = __builtin_amdgcn_mfma_f32_16x16x32_bf16(a00, w1f0, c0, 0,0,0);
        c1 = __builtin_amdgcn_mfma_f32_16x16x32_bf16(a10, w1f0, c1, 0,0,0);
        c0 = __builtin_amdgcn_mfma_f32_16x16x32_bf16(a01, w1f1, c0, 0,0,0);
        c1 = __builtin_amdgcn_mfma_f32_16x16x32_bf16(a11, w1f1, c1, 0,0,0);
        #pragma unroll
        for (int r = 0; r < 4; ++r) {
            int row0 = quad * 4 + r;
            sh_tmp[row0 * 72 + col16]        = f2bf(fmaxf(c0[r] + b1v, 0.f));
            sh_tmp[(16 + row0) * 72 + col16] = f2bf(fmaxf(c1[r] + b1v, 0.f));
        }
    }
    __syncthreads();

    // ---------------- Phase D2: out = tmp @ Wo2 + bo2 -> global (fp32) ----------------
    {
        bf16x8 a00 = *(const bf16x8*)(sh_tmp + l15 * 72 + 0  + quad * 8);
        bf16x8 a01 = *(const bf16x8*)(sh_tmp + l15 * 72 + 32 + quad * 8);
        bf16x8 a10 = *(const bf16x8*)(sh_tmp + (16 + l15) * 72 + 0  + quad * 8);
        bf16x8 a11 = *(const bf16x8*)(sh_tmp + (16 + l15) * 72 + 32 + quad * 8);
        f32x4 c0 = {0.f,0.f,0.f,0.f}, c1 = {0.f,0.f,0.f,0.f};
        c0 = __builtin_amdgcn_mfma_f32_16x16x32_bf16(a00, w2f0, c0, 0,0,0);
        c1 = __builtin_amdgcn_mfma_f32_16x16x32_bf16(a10, w2f0, c1, 0,0,0);
        c0 = __builtin_amdgcn_mfma_f32_16x16x32_bf16(a01, w2f1, c0, 0,0,0);
        c1 = __builtin_amdgcn_mfma_f32_16x16x32_bf16(a11, w2f1, c1, 0,0,0);
        #pragma unroll
        for (int r = 0; r < 4; ++r) {
            int row0 = quad * 4 + r;
            out[((b * T_ + row0) * N_ + n) * D_ + col16] = c0[r] + b2v;
            int row1 = 16 + row0;
            if (row1 < T_)
                out[((b * T_ + row1) * N_ + n) * D_ + col16] = c1[r] + b2v;
        }
    }
}

extern "C" void kernel_launch(void* const* d_in, const int* in_sizes, int n_in,
                              void* d_out, int out_size, void* d_ws, size_t ws_size,
                              hipStream_t stream) {
    (void)in_sizes; (void)n_in; (void)out_size; (void)d_ws; (void)ws_size;
    const float* x   = (const float*)d_in[0];
    const float* ste = (const float*)d_in[1];
    const float* Wq  = (const float*)d_in[2];
    const float* bq  = (const float*)d_in[3];
    const float* Wk  = (const float*)d_in[4];
    const float* bk  = (const float*)d_in[5];
    const float* Wv  = (const float*)d_in[6];
    const float* bv  = (const float*)d_in[7];
    const float* Wo1 = (const float*)d_in[8];
    const float* bo1 = (const float*)d_in[9];
    const float* Wo2 = (const float*)d_in[10];
    const float* bo2 = (const float*)d_in[11];

    ta_repack<<<dim3(16), dim3(256), 0, stream>>>(Wq, Wk, Wv, Wo1, Wo2);
    ta_mfma<<<dim3(N_, B_), dim3(256), 0, stream>>>(
        x, ste, bq, bk, bv, bo1, bo2, (float*)d_out);
}